// Round 1
// baseline (8927.221 us; speedup 1.0000x reference)
//
#include <hip/hip_runtime.h>
#include <hip/hip_bf16.h>

// 12-layer GPT2-ish forward with LoRA + KV fake-quant, bf16 MFMA internals.
// B=4 T=1024 D=1024 H=16 HD=64 L=12 R=32, SCALING=2.0, EPS=1e-5, QMAX=255.

typedef __bf16 bf16x8 __attribute__((ext_vector_type(8)));
typedef float f32x4 __attribute__((ext_vector_type(4)));

static __device__ __forceinline__ float bf2f(unsigned short u) {
    union { unsigned int i; float f; } c; c.i = ((unsigned int)u) << 16; return c.f;
}
static __device__ __forceinline__ unsigned short f2bf(float f) {
    unsigned int u = __float_as_uint(f);
    u += 0x7fffu + ((u >> 16) & 1u);   // RNE
    return (unsigned short)(u >> 16);
}

// ---------------- embedding ----------------
__global__ __launch_bounds__(256) void k_embed(const int* __restrict__ ids,
        const float* __restrict__ wte, const float* __restrict__ wpe,
        float* __restrict__ h) {
    int row = blockIdx.x;          // b*1024 + t
    int t = row & 1023;
    int id = ids[row];
    int d = threadIdx.x * 4;
    float4 a = *(const float4*)(wte + (size_t)id * 1024 + d);
    float4 b = *(const float4*)(wpe + (size_t)t * 1024 + d);
    float4 o = make_float4(a.x + b.x, a.y + b.y, a.z + b.z, a.w + b.w);
    *(float4*)(h + (size_t)row * 1024 + d) = o;
}

// ---------------- layernorm (f32 in; bf16 or f32 out) ----------------
template <bool BF16OUT>
__global__ __launch_bounds__(256) void k_ln(const float* __restrict__ h,
        const float* __restrict__ g, const float* __restrict__ be,
        unsigned short* __restrict__ xo, float* __restrict__ fo) {
    int row = blockIdx.x, tid = threadIdx.x;
    float4 v = *(const float4*)(h + (size_t)row * 1024 + tid * 4);
    float s = v.x + v.y + v.z + v.w;
    for (int off = 32; off; off >>= 1) s += __shfl_down(s, off);
    __shared__ float red[8];
    int wid = tid >> 6, lane = tid & 63;
    if (!lane) red[wid] = s;
    __syncthreads();
    float mean = (red[0] + red[1] + red[2] + red[3]) * (1.f / 1024.f);
    float dx = v.x - mean, dy = v.y - mean, dz = v.z - mean, dw = v.w - mean;
    float q = dx * dx + dy * dy + dz * dz + dw * dw;
    for (int off = 32; off; off >>= 1) q += __shfl_down(q, off);
    if (!lane) red[4 + wid] = q;
    __syncthreads();
    float var = (red[4] + red[5] + red[6] + red[7]) * (1.f / 1024.f);
    float inv = 1.0f / sqrtf(var + 1e-5f);
    float4 gv = *(const float4*)(g + tid * 4);
    float4 bv = *(const float4*)(be + tid * 4);
    float y0 = dx * inv * gv.x + bv.x;
    float y1 = dy * inv * gv.y + bv.y;
    float y2 = dz * inv * gv.z + bv.z;
    float y3 = dw * inv * gv.w + bv.w;
    if (BF16OUT) {
        ushort4 o;
        o.x = f2bf(y0); o.y = f2bf(y1); o.z = f2bf(y2); o.w = f2bf(y3);
        *(ushort4*)(xo + (size_t)row * 1024 + tid * 4) = o;
    } else {
        *(float4*)(fo + (size_t)row * 1024 + tid * 4) = make_float4(y0, y1, y2, y3);
    }
}

// ---------------- LoRA-A: tmp[M][32] = bf16( A[M][K] @ la[K][32] ) ----------------
__global__ __launch_bounds__(256) void k_lora_a(const unsigned short* __restrict__ x,
        const float* __restrict__ la, unsigned short* __restrict__ tmp, int K) {
    int m = blockIdx.x * 8 + (threadIdx.x >> 5);
    int r = threadIdx.x & 31;
    const unsigned short* xr = x + (size_t)m * K;
    float acc = 0.f;
    for (int k0 = 0; k0 < K; k0 += 8) {
        uint4 xv = *(const uint4*)(xr + k0);
        const unsigned short* xs = (const unsigned short*)&xv;
#pragma unroll
        for (int i = 0; i < 8; ++i) acc += bf2f(xs[i]) * la[(size_t)(k0 + i) * 32 + r];
    }
    tmp[(size_t)m * 32 + r] = f2bf(acc);
}

// ---------------- per-layer weight prep: f32 [K][N] -> bf16 [N][K] (lb scaled 2x) ----------------
__global__ __launch_bounds__(256) void k_prep(
        const float* aw, const float* pw, const float* fw, const float* mw,
        const float* alb, const float* plb, const float* flb, const float* mlb,
        unsigned short* WTq, unsigned short* WTp, unsigned short* WTf, unsigned short* WTm,
        unsigned short* LTq, unsigned short* LTp, unsigned short* LTf, unsigned short* LTm) {
    int bid = blockIdx.x;
    const float* src; unsigned short* dst; int K, N, ntn, local; float scale = 1.f;
    if      (bid < 768)  { src = aw;  dst = WTq; K = 1024; N = 3072; ntn = 48; local = bid; }
    else if (bid < 1024) { src = pw;  dst = WTp; K = 1024; N = 1024; ntn = 16; local = bid - 768; }
    else if (bid < 2048) { src = fw;  dst = WTf; K = 1024; N = 4096; ntn = 64; local = bid - 1024; }
    else if (bid < 3072) { src = mw;  dst = WTm; K = 4096; N = 1024; ntn = 16; local = bid - 2048; }
    else if (bid < 3120) { src = alb; dst = LTq; K = 32;   N = 3072; ntn = 48; local = bid - 3072; scale = 2.f; }
    else if (bid < 3136) { src = plb; dst = LTp; K = 32;   N = 1024; ntn = 16; local = bid - 3120; scale = 2.f; }
    else if (bid < 3200) { src = flb; dst = LTf; K = 32;   N = 4096; ntn = 64; local = bid - 3136; scale = 2.f; }
    else                 { src = mlb; dst = LTm; K = 32;   N = 1024; ntn = 16; local = bid - 3200; scale = 2.f; }
    int kt = local / ntn, nt = local % ntn;
    int k0 = kt * 64, n0 = nt * 64;
    __shared__ unsigned short Tl[64][72];
    int tid = threadIdx.x;
    int cr = tid >> 6;     // 0..3
    int cc = tid & 63;     // 0..63
#pragma unroll
    for (int p = 0; p < 16; ++p) {
        int kl = p * 4 + cr;
        if (k0 + kl < K) Tl[kl][cc] = f2bf(src[(size_t)(k0 + kl) * N + n0 + cc] * scale);
    }
    __syncthreads();
#pragma unroll
    for (int p = 0; p < 16; ++p) {
        int nl = p * 4 + cr;
        int kl = cc;
        if (k0 + kl < K) dst[(size_t)(n0 + nl) * K + k0 + kl] = Tl[kl][nl];
    }
}

// ---------------- GEMM: out[M][N] = A_bf16[M][K] @ WT_bf16[N][K]^T + bias (+LoRA K-ext) ----------------
// EPI: 0 = write f32 ; 1 = +residual, write f32 ; 2 = GELU, write bf16
template <int EPI>
__global__ __launch_bounds__(256) void k_gemm(
        const unsigned short* __restrict__ A, const unsigned short* __restrict__ WT,
        const float* __restrict__ bias, const unsigned short* __restrict__ tmpA,
        const unsigned short* __restrict__ lbT, const float* __restrict__ res,
        float* __restrict__ outF, unsigned short* __restrict__ outH, int N, int K) {
    __shared__ unsigned short Al[128 * 40];
    __shared__ unsigned short Bl[128 * 40];
    int tid = threadIdx.x;
    int nBase = blockIdx.x * 128, rowBase = blockIdx.y * 128;
    int w = tid >> 6, lane = tid & 63;
    int wr = w >> 1, wc = w & 1;
    int lrow = lane & 15, lk8 = (lane >> 4) * 8;
    f32x4 acc[4][4];
#pragma unroll
    for (int i = 0; i < 4; ++i)
#pragma unroll
        for (int j = 0; j < 4; ++j) acc[i][j] = f32x4{0.f, 0.f, 0.f, 0.f};
    int nk = K >> 5;
    int sr = tid >> 2;          // staging row 0..63
    int sk = (tid & 3) * 8;     // 0,8,16,24
    for (int kt = 0; kt <= nk; ++kt) {
        __syncthreads();
        bool mn = kt < nk;
#pragma unroll
        for (int p = 0; p < 2; ++p) {
            int r = p * 64 + sr;
            const unsigned short* sa = mn ? A + (size_t)(rowBase + r) * K + kt * 32 + sk
                                          : tmpA + (size_t)(rowBase + r) * 32 + sk;
            *(uint4*)&Al[r * 40 + sk] = *(const uint4*)sa;
            const unsigned short* sb = mn ? WT + (size_t)(nBase + r) * K + kt * 32 + sk
                                          : lbT + (size_t)(nBase + r) * 32 + sk;
            *(uint4*)&Bl[r * 40 + sk] = *(const uint4*)sb;
        }
        __syncthreads();
        bf16x8 af[4], bfr[4];
#pragma unroll
        for (int mt = 0; mt < 4; ++mt) af[mt] = *(const bf16x8*)&Al[(wr * 64 + mt * 16 + lrow) * 40 + lk8];
#pragma unroll
        for (int nt = 0; nt < 4; ++nt) bfr[nt] = *(const bf16x8*)&Bl[(wc * 64 + nt * 16 + lrow) * 40 + lk8];
#pragma unroll
        for (int mt = 0; mt < 4; ++mt)
#pragma unroll
            for (int nt = 0; nt < 4; ++nt)
                acc[mt][nt] = __builtin_amdgcn_mfma_f32_16x16x32_bf16(af[mt], bfr[nt], acc[mt][nt], 0, 0, 0);
    }
    int lq = lane >> 4;
#pragma unroll
    for (int nt = 0; nt < 4; ++nt) {
        int col = nBase + wc * 64 + nt * 16 + lrow;
        float bv = bias[col];
#pragma unroll
        for (int mt = 0; mt < 4; ++mt) {
            int row0 = rowBase + wr * 64 + mt * 16 + lq * 4;
#pragma unroll
            for (int rg = 0; rg < 4; ++rg) {
                int row = row0 + rg;
                float v = acc[mt][nt][rg] + bv;
                size_t idx = (size_t)row * N + col;
                if (EPI == 1) v += res[idx];
                if (EPI == 2) {
                    v = 0.5f * v * (1.f + erff(v * 0.70710678118654752f));
                    outH[idx] = f2bf(v);
                } else {
                    outF[idx] = v;
                }
            }
        }
    }
}

// ---------------- split heads + KV fake-quant; V stored transposed per head ----------------
__global__ __launch_bounds__(256) void k_headq(const float* __restrict__ qkv,
        const float* __restrict__ kvmin, const float* __restrict__ kvmax, int layer,
        unsigned short* __restrict__ qh, unsigned short* __restrict__ kh,
        unsigned short* __restrict__ vh) {
    int t0 = blockIdx.x * 64;
    int bh = blockIdx.y;
    int b = bh >> 4, hh = bh & 15;
    float mnv = kvmin[layer], mxv = kvmax[layer];
    float s = (mxv - mnv) * (1.f / 255.f);
    float zp = rintf(-mnv / s);
    float inv_s = 1.f / s;
    int tid = threadIdx.x;
    int rl = tid >> 2, dseg = (tid & 3) * 16;
    __shared__ unsigned short Vl[64][72];
    size_t base = ((size_t)(b * 1024 + t0 + rl)) * 3072 + hh * 64 + dseg;
    unsigned short t16[16];
    // q
#pragma unroll
    for (int c = 0; c < 4; ++c) {
        float4 v = *(const float4*)(qkv + base + c * 4);
        t16[c * 4 + 0] = f2bf(v.x); t16[c * 4 + 1] = f2bf(v.y);
        t16[c * 4 + 2] = f2bf(v.z); t16[c * 4 + 3] = f2bf(v.w);
    }
    size_t obase = ((size_t)bh * 1024 + t0 + rl) * 64 + dseg;
    *(uint4*)(qh + obase) = *(uint4*)&t16[0];
    *(uint4*)(qh + obase + 8) = *(uint4*)&t16[8];
    // k (fake-quant)
#pragma unroll
    for (int c = 0; c < 4; ++c) {
        float4 v = *(const float4*)(qkv + base + 1024 + c * 4);
        float vals[4] = {v.x, v.y, v.z, v.w};
#pragma unroll
        for (int j = 0; j < 4; ++j) {
            float qv = rintf(vals[j] * inv_s) + zp;
            qv = fminf(fmaxf(qv, 0.f), 255.f);
            t16[c * 4 + j] = f2bf((qv - zp) * s);
        }
    }
    *(uint4*)(kh + obase) = *(uint4*)&t16[0];
    *(uint4*)(kh + obase + 8) = *(uint4*)&t16[8];
    // v (fake-quant) -> LDS -> transposed store
#pragma unroll
    for (int c = 0; c < 4; ++c) {
        float4 v = *(const float4*)(qkv + base + 2048 + c * 4);
        float vals[4] = {v.x, v.y, v.z, v.w};
#pragma unroll
        for (int j = 0; j < 4; ++j) {
            float qv = rintf(vals[j] * inv_s) + zp;
            qv = fminf(fmaxf(qv, 0.f), 255.f);
            Vl[rl][dseg + c * 4 + j] = f2bf((qv - zp) * s);
        }
    }
    __syncthreads();
    int dl = rl, tseg = dseg;
#pragma unroll
    for (int j = 0; j < 16; ++j) t16[j] = Vl[tseg + j][dl];
    size_t vbase = ((size_t)bh * 64 + dl) * 1024 + t0 + tseg;
    *(uint4*)(vh + vbase) = *(uint4*)&t16[0];
    *(uint4*)(vh + vbase + 8) = *(uint4*)&t16[8];
}

// ---------------- flash attention (causal), 64 q-rows/block, 4 waves ----------------
__global__ __launch_bounds__(256) void k_attn(const unsigned short* __restrict__ qh,
        const unsigned short* __restrict__ kh, const unsigned short* __restrict__ vh,
        unsigned short* __restrict__ o) {
    int qb = blockIdx.x, bh = blockIdx.y;
    int b = bh >> 4, hh = bh & 15;
    int tid = threadIdx.x, w = tid >> 6, lane = tid & 63;
    int lrow = lane & 15, lq = lane >> 4, lk8 = lq * 8;
    __shared__ unsigned short Kl[64][72];
    __shared__ unsigned short Vt[64][72];
    __shared__ unsigned short Pl[4][16][72];
    int qrow = qb * 64 + w * 16 + lrow;
    bf16x8 aq[2];
    aq[0] = *(const bf16x8*)(qh + ((size_t)bh * 1024 + qrow) * 64 + lk8);
    aq[1] = *(const bf16x8*)(qh + ((size_t)bh * 1024 + qrow) * 64 + 32 + lk8);
    f32x4 od[4];
#pragma unroll
    for (int i = 0; i < 4; ++i) od[i] = f32x4{0.f, 0.f, 0.f, 0.f};
    float mrun[4] = {-1e30f, -1e30f, -1e30f, -1e30f};
    float lrun[4] = {0.f, 0.f, 0.f, 0.f};
    int rl = tid >> 2, seg = (tid & 3) * 16;
    for (int kb = 0; kb <= qb; ++kb) {
        __syncthreads();
        {
            size_t kbase = ((size_t)bh * 1024 + kb * 64 + rl) * 64 + seg;
            *(uint4*)&Kl[rl][seg] = *(const uint4*)(kh + kbase);
            *(uint4*)&Kl[rl][seg + 8] = *(const uint4*)(kh + kbase + 8);
            size_t vbase = ((size_t)bh * 64 + rl) * 1024 + kb * 64 + seg;
            *(uint4*)&Vt[rl][seg] = *(const uint4*)(vh + vbase);
            *(uint4*)&Vt[rl][seg + 8] = *(const uint4*)(vh + vbase + 8);
        }
        __syncthreads();
        f32x4 st[4];
#pragma unroll
        for (int ktile = 0; ktile < 4; ++ktile) {
            f32x4 sacc = f32x4{0.f, 0.f, 0.f, 0.f};
#pragma unroll
            for (int dh = 0; dh < 2; ++dh) {
                bf16x8 bk = *(const bf16x8*)&Kl[ktile * 16 + lrow][dh * 32 + lk8];
                sacc = __builtin_amdgcn_mfma_f32_16x16x32_bf16(aq[dh], bk, sacc, 0, 0, 0);
            }
            st[ktile] = sacc * 0.125f;   // 1/sqrt(64)
        }
        if (kb == qb) {
#pragma unroll
            for (int ktile = 0; ktile < 4; ++ktile) {
                int kidx = kb * 64 + ktile * 16 + lrow;
#pragma unroll
                for (int rg = 0; rg < 4; ++rg) {
                    int qidx = qb * 64 + w * 16 + lq * 4 + rg;
                    if (kidx > qidx) st[ktile][rg] = -1e30f;
                }
            }
        }
        float corr[4];
#pragma unroll
        for (int rg = 0; rg < 4; ++rg) {
            float x = fmaxf(fmaxf(st[0][rg], st[1][rg]), fmaxf(st[2][rg], st[3][rg]));
            x = fmaxf(x, __shfl_xor(x, 1));
            x = fmaxf(x, __shfl_xor(x, 2));
            x = fmaxf(x, __shfl_xor(x, 4));
            x = fmaxf(x, __shfl_xor(x, 8));
            float mnew = fmaxf(mrun[rg], x);
            float sum = 0.f;
#pragma unroll
            for (int ktile = 0; ktile < 4; ++ktile) {
                st[ktile][rg] = expf(st[ktile][rg] - mnew);
                sum += st[ktile][rg];
            }
            sum += __shfl_xor(sum, 1);
            sum += __shfl_xor(sum, 2);
            sum += __shfl_xor(sum, 4);
            sum += __shfl_xor(sum, 8);
            corr[rg] = expf(mrun[rg] - mnew);
            lrun[rg] = lrun[rg] * corr[rg] + sum;
            mrun[rg] = mnew;
        }
#pragma unroll
        for (int dt = 0; dt < 4; ++dt)
#pragma unroll
            for (int rg = 0; rg < 4; ++rg) od[dt][rg] *= corr[rg];
#pragma unroll
        for (int ktile = 0; ktile < 4; ++ktile)
#pragma unroll
            for (int rg = 0; rg < 4; ++rg)
                Pl[w][lq * 4 + rg][ktile * 16 + lrow] = f2bf(st[ktile][rg]);
        __syncthreads();
        bf16x8 pa[2];
        pa[0] = *(const bf16x8*)&Pl[w][lrow][lk8];
        pa[1] = *(const bf16x8*)&Pl[w][lrow][32 + lk8];
#pragma unroll
        for (int dt = 0; dt < 4; ++dt) {
#pragma unroll
            for (int kh2 = 0; kh2 < 2; ++kh2) {
                bf16x8 bv = *(const bf16x8*)&Vt[dt * 16 + lrow][kh2 * 32 + lk8];
                od[dt] = __builtin_amdgcn_mfma_f32_16x16x32_bf16(pa[kh2], bv, od[dt], 0, 0, 0);
            }
        }
    }
#pragma unroll
    for (int dt = 0; dt < 4; ++dt) {
#pragma unroll
        for (int rg = 0; rg < 4; ++rg) {
            int row = qb * 64 + w * 16 + lq * 4 + rg;
            float val = od[dt][rg] / lrun[rg];
            o[((size_t)(b * 1024 + row)) * 1024 + hh * 64 + dt * 16 + lrow] = f2bf(val);
        }
    }
}

// ---------------- host orchestration ----------------
extern "C" void kernel_launch(void* const* d_in, const int* in_sizes, int n_in,
                              void* d_out, int out_size, void* d_ws, size_t ws_size,
                              hipStream_t stream) {
    const int*   ids      = (const int*)d_in[0];
    const float* wte      = (const float*)d_in[1];
    const float* wpe      = (const float*)d_in[2];
    const float* ln1_g    = (const float*)d_in[3];
    const float* ln1_b    = (const float*)d_in[4];
    const float* attn_w   = (const float*)d_in[5];
    const float* attn_b   = (const float*)d_in[6];
    const float* attn_la  = (const float*)d_in[7];
    const float* attn_lb  = (const float*)d_in[8];
    const float* proj_w   = (const float*)d_in[9];
    const float* proj_b   = (const float*)d_in[10];
    const float* proj_la  = (const float*)d_in[11];
    const float* proj_lb  = (const float*)d_in[12];
    const float* ln2_g    = (const float*)d_in[13];
    const float* ln2_b    = (const float*)d_in[14];
    const float* fc_w     = (const float*)d_in[15];
    const float* fc_b     = (const float*)d_in[16];
    const float* fc_la    = (const float*)d_in[17];
    const float* fc_lb    = (const float*)d_in[18];
    const float* mproj_w  = (const float*)d_in[19];
    const float* mproj_b  = (const float*)d_in[20];
    const float* mproj_la = (const float*)d_in[21];
    const float* mproj_lb = (const float*)d_in[22];
    const float* kv_min   = (const float*)d_in[23];
    const float* kv_max   = (const float*)d_in[24];
    const float* lnf_g    = (const float*)d_in[25];
    const float* lnf_b    = (const float*)d_in[26];

    char* ws = (char*)d_ws;
    size_t off = 0;
    auto alloc = [&](size_t bytes) -> char* {
        char* p = ws + off;
        off = (off + bytes + 255) & ~(size_t)255;
        return p;
    };
    float*          h   = (float*)alloc(4096ull * 1024 * 4);
    unsigned short* xb  = (unsigned short*)alloc(4096ull * 1024 * 2);
    float*          qkv = (float*)alloc(4096ull * 3072 * 4);
    unsigned short* tmp = (unsigned short*)alloc(4096ull * 32 * 2);
    unsigned short* qhb = (unsigned short*)alloc(64ull * 1024 * 64 * 2);
    unsigned short* khb = (unsigned short*)alloc(64ull * 1024 * 64 * 2);
    unsigned short* vhb = (unsigned short*)alloc(64ull * 64 * 1024 * 2);
    unsigned short* ob  = (unsigned short*)alloc(4096ull * 1024 * 2);
    unsigned short* mb  = (unsigned short*)alloc(4096ull * 4096 * 2);
    unsigned short* WTq = (unsigned short*)alloc(3072ull * 1024 * 2);
    unsigned short* WTp = (unsigned short*)alloc(1024ull * 1024 * 2);
    unsigned short* WTf = (unsigned short*)alloc(4096ull * 1024 * 2);
    unsigned short* WTm = (unsigned short*)alloc(1024ull * 4096 * 2);
    unsigned short* LTq = (unsigned short*)alloc(3072ull * 32 * 2);
    unsigned short* LTp = (unsigned short*)alloc(1024ull * 32 * 2);
    unsigned short* LTf = (unsigned short*)alloc(4096ull * 32 * 2);
    unsigned short* LTm = (unsigned short*)alloc(1024ull * 32 * 2);

    k_embed<<<4096, 256, 0, stream>>>(ids, wte, wpe, h);
    for (int l = 0; l < 12; ++l) {
        k_prep<<<3216, 256, 0, stream>>>(
            attn_w + (size_t)l * 1024 * 3072, proj_w + (size_t)l * 1024 * 1024,
            fc_w + (size_t)l * 1024 * 4096, mproj_w + (size_t)l * 4096 * 1024,
            attn_lb + (size_t)l * 32 * 3072, proj_lb + (size_t)l * 32 * 1024,
            fc_lb + (size_t)l * 32 * 4096, mproj_lb + (size_t)l * 32 * 1024,
            WTq, WTp, WTf, WTm, LTq, LTp, LTf, LTm);
        k_ln<true><<<4096, 256, 0, stream>>>(h, ln1_g + l * 1024, ln1_b + l * 1024, xb, nullptr);
        k_lora_a<<<512, 256, 0, stream>>>(xb, attn_la + (size_t)l * 1024 * 32, tmp, 1024);
        k_gemm<0><<<dim3(24, 32), 256, 0, stream>>>(xb, WTq, attn_b + l * 3072, tmp, LTq,
                                                    nullptr, qkv, nullptr, 3072, 1024);
        k_headq<<<dim3(16, 64), 256, 0, stream>>>(qkv, kv_min, kv_max, l, qhb, khb, vhb);
        k_attn<<<dim3(16, 64), 256, 0, stream>>>(qhb, khb, vhb, ob);
        k_lora_a<<<512, 256, 0, stream>>>(ob, proj_la + (size_t)l * 1024 * 32, tmp, 1024);
        k_gemm<1><<<dim3(8, 32), 256, 0, stream>>>(ob, WTp, proj_b + l * 1024, tmp, LTp,
                                                   h, h, nullptr, 1024, 1024);
        k_ln<true><<<4096, 256, 0, stream>>>(h, ln2_g + l * 1024, ln2_b + l * 1024, xb, nullptr);
        k_lora_a<<<512, 256, 0, stream>>>(xb, fc_la + (size_t)l * 1024 * 32, tmp, 1024);
        k_gemm<2><<<dim3(32, 32), 256, 0, stream>>>(xb, WTf, fc_b + l * 4096, tmp, LTf,
                                                    nullptr, nullptr, mb, 4096, 1024);
        k_lora_a<<<512, 256, 0, stream>>>(mb, mproj_la + (size_t)l * 4096 * 32, tmp, 4096);
        k_gemm<1><<<dim3(8, 32), 256, 0, stream>>>(mb, WTm, mproj_b + l * 1024, tmp, LTm,
                                                   h, h, nullptr, 1024, 4096);
    }
    k_ln<false><<<4096, 256, 0, stream>>>(h, lnf_g, lnf_b, nullptr, (float*)d_out);
}

// Round 2
// 5318.211 us; speedup vs baseline: 1.6786x; 1.6786x over previous
//
#include <hip/hip_runtime.h>
#include <hip/hip_bf16.h>

// 12-layer GPT2-ish forward with LoRA + KV fake-quant, bf16 MFMA internals.
// B=4 T=1024 D=1024 H=16 HD=64 L=12 R=32, SCALING=2.0, EPS=1e-5, QMAX=255.

typedef __bf16 bf16x8 __attribute__((ext_vector_type(8)));
typedef float f32x4 __attribute__((ext_vector_type(4)));

static __device__ __forceinline__ float bf2f(unsigned short u) {
    union { unsigned int i; float f; } c; c.i = ((unsigned int)u) << 16; return c.f;
}
static __device__ __forceinline__ unsigned short f2bf(float f) {
    unsigned int u = __float_as_uint(f);
    u += 0x7fffu + ((u >> 16) & 1u);   // RNE
    return (unsigned short)(u >> 16);
}

// ---------------- embedding ----------------
__global__ __launch_bounds__(256) void k_embed(const int* __restrict__ ids,
        const float* __restrict__ wte, const float* __restrict__ wpe,
        float* __restrict__ h) {
    int row = blockIdx.x;          // b*1024 + t
    int t = row & 1023;
    int id = ids[row];
    int d = threadIdx.x * 4;
    float4 a = *(const float4*)(wte + (size_t)id * 1024 + d);
    float4 b = *(const float4*)(wpe + (size_t)t * 1024 + d);
    float4 o = make_float4(a.x + b.x, a.y + b.y, a.z + b.z, a.w + b.w);
    *(float4*)(h + (size_t)row * 1024 + d) = o;
}

// ---------------- layernorm (f32 in; bf16 or f32 out) ----------------
template <bool BF16OUT>
__global__ __launch_bounds__(256) void k_ln(const float* __restrict__ h,
        const float* __restrict__ g, const float* __restrict__ be,
        unsigned short* __restrict__ xo, float* __restrict__ fo) {
    int row = blockIdx.x, tid = threadIdx.x;
    float4 v = *(const float4*)(h + (size_t)row * 1024 + tid * 4);
    float s = v.x + v.y + v.z + v.w;
    for (int off = 32; off; off >>= 1) s += __shfl_down(s, off);
    __shared__ float red[8];
    int wid = tid >> 6, lane = tid & 63;
    if (!lane) red[wid] = s;
    __syncthreads();
    float mean = (red[0] + red[1] + red[2] + red[3]) * (1.f / 1024.f);
    float dx = v.x - mean, dy = v.y - mean, dz = v.z - mean, dw = v.w - mean;
    float q = dx * dx + dy * dy + dz * dz + dw * dw;
    for (int off = 32; off; off >>= 1) q += __shfl_down(q, off);
    if (!lane) red[4 + wid] = q;
    __syncthreads();
    float var = (red[4] + red[5] + red[6] + red[7]) * (1.f / 1024.f);
    float inv = 1.0f / sqrtf(var + 1e-5f);
    float4 gv = *(const float4*)(g + tid * 4);
    float4 bv = *(const float4*)(be + tid * 4);
    float y0 = dx * inv * gv.x + bv.x;
    float y1 = dy * inv * gv.y + bv.y;
    float y2 = dz * inv * gv.z + bv.z;
    float y3 = dw * inv * gv.w + bv.w;
    if (BF16OUT) {
        ushort4 o;
        o.x = f2bf(y0); o.y = f2bf(y1); o.z = f2bf(y2); o.w = f2bf(y3);
        *(ushort4*)(xo + (size_t)row * 1024 + tid * 4) = o;
    } else {
        *(float4*)(fo + (size_t)row * 1024 + tid * 4) = make_float4(y0, y1, y2, y3);
    }
}

// ---------------- LoRA-A via MFMA: tmp[M][32] = bf16( A[M][K] @ laT[32][K]^T ) ----------------
// 1 wave / block, 16 rows / block, no LDS, no barriers (loads pipeline freely).
__global__ __launch_bounds__(64) void k_lora_mfma(const unsigned short* __restrict__ A,
        const unsigned short* __restrict__ laT, unsigned short* __restrict__ tmp, int K) {
    int rowBase = blockIdx.x * 16;
    int lane = threadIdx.x;
    int lrow = lane & 15, lk8 = (lane >> 4) * 8;
    f32x4 acc0 = {0.f, 0.f, 0.f, 0.f}, acc1 = {0.f, 0.f, 0.f, 0.f};
    const unsigned short* arow = A + (size_t)(rowBase + lrow) * K + lk8;
    const unsigned short* b0p = laT + (size_t)lrow * K + lk8;
    const unsigned short* b1p = laT + (size_t)(16 + lrow) * K + lk8;
#pragma unroll 2
    for (int kt = 0; kt < K; kt += 32) {
        bf16x8 af = *(const bf16x8*)(arow + kt);
        bf16x8 b0 = *(const bf16x8*)(b0p + kt);
        bf16x8 b1 = *(const bf16x8*)(b1p + kt);
        acc0 = __builtin_amdgcn_mfma_f32_16x16x32_bf16(af, b0, acc0, 0, 0, 0);
        acc1 = __builtin_amdgcn_mfma_f32_16x16x32_bf16(af, b1, acc1, 0, 0, 0);
    }
    int lq = lane >> 4;
#pragma unroll
    for (int rg = 0; rg < 4; ++rg) {
        int row = rowBase + lq * 4 + rg;
        tmp[(size_t)row * 32 + lrow] = f2bf(acc0[rg]);
        tmp[(size_t)row * 32 + 16 + lrow] = f2bf(acc1[rg]);
    }
}

// ---------------- per-layer weight prep: f32 [K][N] -> bf16 [N][K] ----------------
// lb tensors pre-scaled by 2 (LoRA SCALING); la tensors transposed to [32][K].
__global__ __launch_bounds__(256) void k_prep(
        const float* aw, const float* pw, const float* fw, const float* mw,
        const float* alb, const float* plb, const float* flb, const float* mlb,
        const float* ala, const float* pla, const float* fla, const float* mla,
        unsigned short* WTq, unsigned short* WTp, unsigned short* WTf, unsigned short* WTm,
        unsigned short* LTq, unsigned short* LTp, unsigned short* LTf, unsigned short* LTm,
        unsigned short* LAq, unsigned short* LAp, unsigned short* LAf, unsigned short* LAm) {
    int bid = blockIdx.x;
    const float* src; unsigned short* dst; int K, N, ntn, local; float scale = 1.f;
    if      (bid < 768)  { src = aw;  dst = WTq; K = 1024; N = 3072; ntn = 48; local = bid; }
    else if (bid < 1024) { src = pw;  dst = WTp; K = 1024; N = 1024; ntn = 16; local = bid - 768; }
    else if (bid < 2048) { src = fw;  dst = WTf; K = 1024; N = 4096; ntn = 64; local = bid - 1024; }
    else if (bid < 3072) { src = mw;  dst = WTm; K = 4096; N = 1024; ntn = 16; local = bid - 2048; }
    else if (bid < 3120) { src = alb; dst = LTq; K = 32;   N = 3072; ntn = 48; local = bid - 3072; scale = 2.f; }
    else if (bid < 3136) { src = plb; dst = LTp; K = 32;   N = 1024; ntn = 16; local = bid - 3120; scale = 2.f; }
    else if (bid < 3200) { src = flb; dst = LTf; K = 32;   N = 4096; ntn = 64; local = bid - 3136; scale = 2.f; }
    else if (bid < 3216) { src = mlb; dst = LTm; K = 32;   N = 1024; ntn = 16; local = bid - 3200; scale = 2.f; }
    else if (bid < 3232) { src = ala; dst = LAq; K = 1024; N = 32;   ntn = 1;  local = bid - 3216; }
    else if (bid < 3248) { src = pla; dst = LAp; K = 1024; N = 32;   ntn = 1;  local = bid - 3232; }
    else if (bid < 3264) { src = fla; dst = LAf; K = 1024; N = 32;   ntn = 1;  local = bid - 3248; }
    else                 { src = mla; dst = LAm; K = 4096; N = 32;   ntn = 1;  local = bid - 3264; }
    int kt = local / ntn, nt = local % ntn;
    int k0 = kt * 64, n0 = nt * 64;
    __shared__ unsigned short Tl[64][72];
    int tid = threadIdx.x;
    int cr = tid >> 6;     // 0..3
    int cc = tid & 63;     // 0..63
#pragma unroll
    for (int p = 0; p < 16; ++p) {
        int kl = p * 4 + cr;
        if (k0 + kl < K && n0 + cc < N) Tl[kl][cc] = f2bf(src[(size_t)(k0 + kl) * N + n0 + cc] * scale);
    }
    __syncthreads();
#pragma unroll
    for (int p = 0; p < 16; ++p) {
        int nl = p * 4 + cr;
        int kl = cc;
        if (k0 + kl < K && n0 + nl < N) dst[(size_t)(n0 + nl) * K + k0 + kl] = Tl[kl][nl];
    }
}

// ---------------- GEMM: out[M][N] = A_bf16[M][K] @ WT_bf16[N][K]^T + bias (+LoRA K-ext) ----------------
// EPI: 0 = write f32 ; 1 = +residual, write f32 ; 2 = GELU, write bf16
template <int EPI>
__global__ __launch_bounds__(256) void k_gemm(
        const unsigned short* __restrict__ A, const unsigned short* __restrict__ WT,
        const float* __restrict__ bias, const unsigned short* __restrict__ tmpA,
        const unsigned short* __restrict__ lbT, const float* __restrict__ res,
        float* __restrict__ outF, unsigned short* __restrict__ outH, int N, int K) {
    __shared__ unsigned short Al[128 * 40];
    __shared__ unsigned short Bl[128 * 40];
    int tid = threadIdx.x;
    int nBase = blockIdx.x * 128, rowBase = blockIdx.y * 128;
    int w = tid >> 6, lane = tid & 63;
    int wr = w >> 1, wc = w & 1;
    int lrow = lane & 15, lk8 = (lane >> 4) * 8;
    f32x4 acc[4][4];
#pragma unroll
    for (int i = 0; i < 4; ++i)
#pragma unroll
        for (int j = 0; j < 4; ++j) acc[i][j] = f32x4{0.f, 0.f, 0.f, 0.f};
    int nk = K >> 5;
    int sr = tid >> 2;          // staging row 0..63
    int sk = (tid & 3) * 8;     // 0,8,16,24
    for (int kt = 0; kt <= nk; ++kt) {
        __syncthreads();
        bool mn = kt < nk;
#pragma unroll
        for (int p = 0; p < 2; ++p) {
            int r = p * 64 + sr;
            const unsigned short* sa = mn ? A + (size_t)(rowBase + r) * K + kt * 32 + sk
                                          : tmpA + (size_t)(rowBase + r) * 32 + sk;
            *(uint4*)&Al[r * 40 + sk] = *(const uint4*)sa;
            const unsigned short* sb = mn ? WT + (size_t)(nBase + r) * K + kt * 32 + sk
                                          : lbT + (size_t)(nBase + r) * 32 + sk;
            *(uint4*)&Bl[r * 40 + sk] = *(const uint4*)sb;
        }
        __syncthreads();
        bf16x8 af[4], bfr[4];
#pragma unroll
        for (int mt = 0; mt < 4; ++mt) af[mt] = *(const bf16x8*)&Al[(wr * 64 + mt * 16 + lrow) * 40 + lk8];
#pragma unroll
        for (int nt = 0; nt < 4; ++nt) bfr[nt] = *(const bf16x8*)&Bl[(wc * 64 + nt * 16 + lrow) * 40 + lk8];
#pragma unroll
        for (int mt = 0; mt < 4; ++mt)
#pragma unroll
            for (int nt = 0; nt < 4; ++nt)
                acc[mt][nt] = __builtin_amdgcn_mfma_f32_16x16x32_bf16(af[mt], bfr[nt], acc[mt][nt], 0, 0, 0);
    }
    int lq = lane >> 4;
#pragma unroll
    for (int nt = 0; nt < 4; ++nt) {
        int col = nBase + wc * 64 + nt * 16 + lrow;
        float bv = bias[col];
#pragma unroll
        for (int mt = 0; mt < 4; ++mt) {
            int row0 = rowBase + wr * 64 + mt * 16 + lq * 4;
#pragma unroll
            for (int rg = 0; rg < 4; ++rg) {
                int row = row0 + rg;
                float v = acc[mt][nt][rg] + bv;
                size_t idx = (size_t)row * N + col;
                if (EPI == 1) v += res[idx];
                if (EPI == 2) {
                    v = 0.5f * v * (1.f + erff(v * 0.70710678118654752f));
                    outH[idx] = f2bf(v);
                } else {
                    outF[idx] = v;
                }
            }
        }
    }
}

// ---------------- split heads + KV fake-quant; V stored transposed per head ----------------
__global__ __launch_bounds__(256) void k_headq(const float* __restrict__ qkv,
        const float* __restrict__ kvmin, const float* __restrict__ kvmax, int layer,
        unsigned short* __restrict__ qh, unsigned short* __restrict__ kh,
        unsigned short* __restrict__ vh) {
    int t0 = blockIdx.x * 64;
    int bh = blockIdx.y;
    int b = bh >> 4, hh = bh & 15;
    float mnv = kvmin[layer], mxv = kvmax[layer];
    float s = (mxv - mnv) * (1.f / 255.f);
    float zp = rintf(-mnv / s);
    float inv_s = 1.f / s;
    int tid = threadIdx.x;
    int rl = tid >> 2, dseg = (tid & 3) * 16;
    __shared__ unsigned short Vl[64][72];
    size_t base = ((size_t)(b * 1024 + t0 + rl)) * 3072 + hh * 64 + dseg;
    unsigned short t16[16];
    // q
#pragma unroll
    for (int c = 0; c < 4; ++c) {
        float4 v = *(const float4*)(qkv + base + c * 4);
        t16[c * 4 + 0] = f2bf(v.x); t16[c * 4 + 1] = f2bf(v.y);
        t16[c * 4 + 2] = f2bf(v.z); t16[c * 4 + 3] = f2bf(v.w);
    }
    size_t obase = ((size_t)bh * 1024 + t0 + rl) * 64 + dseg;
    *(uint4*)(qh + obase) = *(uint4*)&t16[0];
    *(uint4*)(qh + obase + 8) = *(uint4*)&t16[8];
    // k (fake-quant)
#pragma unroll
    for (int c = 0; c < 4; ++c) {
        float4 v = *(const float4*)(qkv + base + 1024 + c * 4);
        float vals[4] = {v.x, v.y, v.z, v.w};
#pragma unroll
        for (int j = 0; j < 4; ++j) {
            float qv = rintf(vals[j] * inv_s) + zp;
            qv = fminf(fmaxf(qv, 0.f), 255.f);
            t16[c * 4 + j] = f2bf((qv - zp) * s);
        }
    }
    *(uint4*)(kh + obase) = *(uint4*)&t16[0];
    *(uint4*)(kh + obase + 8) = *(uint4*)&t16[8];
    // v (fake-quant) -> LDS -> transposed store
#pragma unroll
    for (int c = 0; c < 4; ++c) {
        float4 v = *(const float4*)(qkv + base + 2048 + c * 4);
        float vals[4] = {v.x, v.y, v.z, v.w};
#pragma unroll
        for (int j = 0; j < 4; ++j) {
            float qv = rintf(vals[j] * inv_s) + zp;
            qv = fminf(fmaxf(qv, 0.f), 255.f);
            Vl[rl][dseg + c * 4 + j] = f2bf((qv - zp) * s);
        }
    }
    __syncthreads();
    int dl = rl, tseg = dseg;
#pragma unroll
    for (int j = 0; j < 16; ++j) t16[j] = Vl[tseg + j][dl];
    size_t vbase = ((size_t)bh * 64 + dl) * 1024 + t0 + tseg;
    *(uint4*)(vh + vbase) = *(uint4*)&t16[0];
    *(uint4*)(vh + vbase + 8) = *(uint4*)&t16[8];
}

// ---------------- flash attention (causal), 64 q-rows/block, 4 waves ----------------
__global__ __launch_bounds__(256) void k_attn(const unsigned short* __restrict__ qh,
        const unsigned short* __restrict__ kh, const unsigned short* __restrict__ vh,
        unsigned short* __restrict__ o) {
    int qb = blockIdx.x, bh = blockIdx.y;
    int b = bh >> 4, hh = bh & 15;
    int tid = threadIdx.x, w = tid >> 6, lane = tid & 63;
    int lrow = lane & 15, lq = lane >> 4, lk8 = lq * 8;
    __shared__ unsigned short Kl[64][72];
    __shared__ unsigned short Vt[64][72];
    __shared__ unsigned short Pl[4][16][72];
    int qrow = qb * 64 + w * 16 + lrow;
    bf16x8 aq[2];
    aq[0] = *(const bf16x8*)(qh + ((size_t)bh * 1024 + qrow) * 64 + lk8);
    aq[1] = *(const bf16x8*)(qh + ((size_t)bh * 1024 + qrow) * 64 + 32 + lk8);
    f32x4 od[4];
#pragma unroll
    for (int i = 0; i < 4; ++i) od[i] = f32x4{0.f, 0.f, 0.f, 0.f};
    float mrun[4] = {-1e30f, -1e30f, -1e30f, -1e30f};
    float lrun[4] = {0.f, 0.f, 0.f, 0.f};
    int rl = tid >> 2, seg = (tid & 3) * 16;
    for (int kb = 0; kb <= qb; ++kb) {
        __syncthreads();
        {
            size_t kbase = ((size_t)bh * 1024 + kb * 64 + rl) * 64 + seg;
            *(uint4*)&Kl[rl][seg] = *(const uint4*)(kh + kbase);
            *(uint4*)&Kl[rl][seg + 8] = *(const uint4*)(kh + kbase + 8);
            size_t vbase = ((size_t)bh * 64 + rl) * 1024 + kb * 64 + seg;
            *(uint4*)&Vt[rl][seg] = *(const uint4*)(vh + vbase);
            *(uint4*)&Vt[rl][seg + 8] = *(const uint4*)(vh + vbase + 8);
        }
        __syncthreads();
        f32x4 st[4];
#pragma unroll
        for (int ktile = 0; ktile < 4; ++ktile) {
            f32x4 sacc = f32x4{0.f, 0.f, 0.f, 0.f};
#pragma unroll
            for (int dh = 0; dh < 2; ++dh) {
                bf16x8 bk = *(const bf16x8*)&Kl[ktile * 16 + lrow][dh * 32 + lk8];
                sacc = __builtin_amdgcn_mfma_f32_16x16x32_bf16(aq[dh], bk, sacc, 0, 0, 0);
            }
            st[ktile] = sacc * 0.125f;   // 1/sqrt(64)
        }
        if (kb == qb) {
#pragma unroll
            for (int ktile = 0; ktile < 4; ++ktile) {
                int kidx = kb * 64 + ktile * 16 + lrow;
#pragma unroll
                for (int rg = 0; rg < 4; ++rg) {
                    int qidx = qb * 64 + w * 16 + lq * 4 + rg;
                    if (kidx > qidx) st[ktile][rg] = -1e30f;
                }
            }
        }
        float corr[4];
#pragma unroll
        for (int rg = 0; rg < 4; ++rg) {
            float x = fmaxf(fmaxf(st[0][rg], st[1][rg]), fmaxf(st[2][rg], st[3][rg]));
            x = fmaxf(x, __shfl_xor(x, 1));
            x = fmaxf(x, __shfl_xor(x, 2));
            x = fmaxf(x, __shfl_xor(x, 4));
            x = fmaxf(x, __shfl_xor(x, 8));
            float mnew = fmaxf(mrun[rg], x);
            float sum = 0.f;
#pragma unroll
            for (int ktile = 0; ktile < 4; ++ktile) {
                st[ktile][rg] = expf(st[ktile][rg] - mnew);
                sum += st[ktile][rg];
            }
            sum += __shfl_xor(sum, 1);
            sum += __shfl_xor(sum, 2);
            sum += __shfl_xor(sum, 4);
            sum += __shfl_xor(sum, 8);
            corr[rg] = expf(mrun[rg] - mnew);
            lrun[rg] = lrun[rg] * corr[rg] + sum;
            mrun[rg] = mnew;
        }
#pragma unroll
        for (int dt = 0; dt < 4; ++dt)
#pragma unroll
            for (int rg = 0; rg < 4; ++rg) od[dt][rg] *= corr[rg];
#pragma unroll
        for (int ktile = 0; ktile < 4; ++ktile)
#pragma unroll
            for (int rg = 0; rg < 4; ++rg)
                Pl[w][lq * 4 + rg][ktile * 16 + lrow] = f2bf(st[ktile][rg]);
        __syncthreads();
        bf16x8 pa[2];
        pa[0] = *(const bf16x8*)&Pl[w][lrow][lk8];
        pa[1] = *(const bf16x8*)&Pl[w][lrow][32 + lk8];
#pragma unroll
        for (int dt = 0; dt < 4; ++dt) {
#pragma unroll
            for (int kh2 = 0; kh2 < 2; ++kh2) {
                bf16x8 bv = *(const bf16x8*)&Vt[dt * 16 + lrow][kh2 * 32 + lk8];
                od[dt] = __builtin_amdgcn_mfma_f32_16x16x32_bf16(pa[kh2], bv, od[dt], 0, 0, 0);
            }
        }
    }
#pragma unroll
    for (int dt = 0; dt < 4; ++dt) {
#pragma unroll
        for (int rg = 0; rg < 4; ++rg) {
            int row = qb * 64 + w * 16 + lq * 4 + rg;
            float val = od[dt][rg] / lrun[rg];
            o[((size_t)(b * 1024 + row)) * 1024 + hh * 64 + dt * 16 + lrow] = f2bf(val);
        }
    }
}

// ---------------- host orchestration ----------------
extern "C" void kernel_launch(void* const* d_in, const int* in_sizes, int n_in,
                              void* d_out, int out_size, void* d_ws, size_t ws_size,
                              hipStream_t stream) {
    const int*   ids      = (const int*)d_in[0];
    const float* wte      = (const float*)d_in[1];
    const float* wpe      = (const float*)d_in[2];
    const float* ln1_g    = (const float*)d_in[3];
    const float* ln1_b    = (const float*)d_in[4];
    const float* attn_w   = (const float*)d_in[5];
    const float* attn_b   = (const float*)d_in[6];
    const float* attn_la  = (const float*)d_in[7];
    const float* attn_lb  = (const float*)d_in[8];
    const float* proj_w   = (const float*)d_in[9];
    const float* proj_b   = (const float*)d_in[10];
    const float* proj_la  = (const float*)d_in[11];
    const float* proj_lb  = (const float*)d_in[12];
    const float* ln2_g    = (const float*)d_in[13];
    const float* ln2_b    = (const float*)d_in[14];
    const float* fc_w     = (const float*)d_in[15];
    const float* fc_b     = (const float*)d_in[16];
    const float* fc_la    = (const float*)d_in[17];
    const float* fc_lb    = (const float*)d_in[18];
    const float* mproj_w  = (const float*)d_in[19];
    const float* mproj_b  = (const float*)d_in[20];
    const float* mproj_la = (const float*)d_in[21];
    const float* mproj_lb = (const float*)d_in[22];
    const float* kv_min   = (const float*)d_in[23];
    const float* kv_max   = (const float*)d_in[24];
    const float* lnf_g    = (const float*)d_in[25];
    const float* lnf_b    = (const float*)d_in[26];

    char* ws = (char*)d_ws;
    size_t off = 0;
    auto alloc = [&](size_t bytes) -> char* {
        char* p = ws + off;
        off = (off + bytes + 255) & ~(size_t)255;
        return p;
    };
    float*          h   = (float*)alloc(4096ull * 1024 * 4);
    unsigned short* xb  = (unsigned short*)alloc(4096ull * 1024 * 2);
    float*          qkv = (float*)alloc(4096ull * 3072 * 4);
    unsigned short* tmp = (unsigned short*)alloc(4096ull * 32 * 2);
    unsigned short* qhb = (unsigned short*)alloc(64ull * 1024 * 64 * 2);
    unsigned short* khb = (unsigned short*)alloc(64ull * 1024 * 64 * 2);
    unsigned short* vhb = (unsigned short*)alloc(64ull * 64 * 1024 * 2);
    unsigned short* ob  = (unsigned short*)alloc(4096ull * 1024 * 2);
    unsigned short* mb  = (unsigned short*)alloc(4096ull * 4096 * 2);
    unsigned short* WTq = (unsigned short*)alloc(3072ull * 1024 * 2);
    unsigned short* WTp = (unsigned short*)alloc(1024ull * 1024 * 2);
    unsigned short* WTf = (unsigned short*)alloc(4096ull * 1024 * 2);
    unsigned short* WTm = (unsigned short*)alloc(1024ull * 4096 * 2);
    unsigned short* LTq = (unsigned short*)alloc(3072ull * 32 * 2);
    unsigned short* LTp = (unsigned short*)alloc(1024ull * 32 * 2);
    unsigned short* LTf = (unsigned short*)alloc(4096ull * 32 * 2);
    unsigned short* LTm = (unsigned short*)alloc(1024ull * 32 * 2);
    unsigned short* LAq = (unsigned short*)alloc(32ull * 1024 * 2);
    unsigned short* LAp = (unsigned short*)alloc(32ull * 1024 * 2);
    unsigned short* LAf = (unsigned short*)alloc(32ull * 1024 * 2);
    unsigned short* LAm = (unsigned short*)alloc(32ull * 4096 * 2);

    k_embed<<<4096, 256, 0, stream>>>(ids, wte, wpe, h);
    for (int l = 0; l < 12; ++l) {
        k_prep<<<3328, 256, 0, stream>>>(
            attn_w + (size_t)l * 1024 * 3072, proj_w + (size_t)l * 1024 * 1024,
            fc_w + (size_t)l * 1024 * 4096, mproj_w + (size_t)l * 4096 * 1024,
            attn_lb + (size_t)l * 32 * 3072, proj_lb + (size_t)l * 32 * 1024,
            fc_lb + (size_t)l * 32 * 4096, mproj_lb + (size_t)l * 32 * 1024,
            attn_la + (size_t)l * 1024 * 32, proj_la + (size_t)l * 1024 * 32,
            fc_la + (size_t)l * 1024 * 32, mproj_la + (size_t)l * 4096 * 32,
            WTq, WTp, WTf, WTm, LTq, LTp, LTf, LTm, LAq, LAp, LAf, LAm);
        k_ln<true><<<4096, 256, 0, stream>>>(h, ln1_g + l * 1024, ln1_b + l * 1024, xb, nullptr);
        k_lora_mfma<<<256, 64, 0, stream>>>(xb, LAq, tmp, 1024);
        k_gemm<0><<<dim3(24, 32), 256, 0, stream>>>(xb, WTq, attn_b + l * 3072, tmp, LTq,
                                                    nullptr, qkv, nullptr, 3072, 1024);
        k_headq<<<dim3(16, 64), 256, 0, stream>>>(qkv, kv_min, kv_max, l, qhb, khb, vhb);
        k_attn<<<dim3(16, 64), 256, 0, stream>>>(qhb, khb, vhb, ob);
        k_lora_mfma<<<256, 64, 0, stream>>>(ob, LAp, tmp, 1024);
        k_gemm<1><<<dim3(8, 32), 256, 0, stream>>>(ob, WTp, proj_b + l * 1024, tmp, LTp,
                                                   h, h, nullptr, 1024, 1024);
        k_ln<true><<<4096, 256, 0, stream>>>(h, ln2_g + l * 1024, ln2_b + l * 1024, xb, nullptr);
        k_lora_mfma<<<256, 64, 0, stream>>>(xb, LAf, tmp, 1024);
        k_gemm<2><<<dim3(32, 32), 256, 0, stream>>>(xb, WTf, fc_b + l * 4096, tmp, LTf,
                                                    nullptr, nullptr, mb, 4096, 1024);
        k_lora_mfma<<<256, 64, 0, stream>>>(mb, LAm, tmp, 4096);
        k_gemm<1><<<dim3(8, 32), 256, 0, stream>>>(mb, WTm, mproj_b + l * 1024, tmp, LTm,
                                                   h, h, nullptr, 1024, 4096);
    }
    k_ln<false><<<4096, 256, 0, stream>>>(h, lnf_g, lnf_b, nullptr, (float*)d_out);
}

// Round 3
// 4959.140 us; speedup vs baseline: 1.8002x; 1.0724x over previous
//
#include <hip/hip_runtime.h>
#include <hip/hip_bf16.h>

// 12-layer GPT2-ish forward with LoRA + KV fake-quant, bf16 MFMA internals.
// B=4 T=1024 D=1024 H=16 HD=64 L=12 R=32, SCALING=2.0, EPS=1e-5, QMAX=255.

typedef __bf16 bf16x8 __attribute__((ext_vector_type(8)));
typedef float f32x4 __attribute__((ext_vector_type(4)));

static __device__ __forceinline__ float bf2f(unsigned short u) {
    union { unsigned int i; float f; } c; c.i = ((unsigned int)u) << 16; return c.f;
}
static __device__ __forceinline__ unsigned short f2bf(float f) {
    unsigned int u = __float_as_uint(f);
    u += 0x7fffu + ((u >> 16) & 1u);   // RNE
    return (unsigned short)(u >> 16);
}

// async global->LDS, 16B per lane; LDS dst must be wave-uniform (HW adds lane*16B)
#define GL2LDS(g, l) __builtin_amdgcn_global_load_lds( \
    (const __attribute__((address_space(1))) unsigned int*)(g), \
    (__attribute__((address_space(3))) unsigned int*)(l), 16, 0, 0)

// ---------------- embedding ----------------
__global__ __launch_bounds__(256) void k_embed(const int* __restrict__ ids,
        const float* __restrict__ wte, const float* __restrict__ wpe,
        float* __restrict__ h) {
    int row = blockIdx.x;          // b*1024 + t
    int t = row & 1023;
    int id = ids[row];
    int d = threadIdx.x * 4;
    float4 a = *(const float4*)(wte + (size_t)id * 1024 + d);
    float4 b = *(const float4*)(wpe + (size_t)t * 1024 + d);
    float4 o = make_float4(a.x + b.x, a.y + b.y, a.z + b.z, a.w + b.w);
    *(float4*)(h + (size_t)row * 1024 + d) = o;
}

// ---------------- layernorm (f32 in; bf16 or f32 out) ----------------
template <bool BF16OUT>
__global__ __launch_bounds__(256) void k_ln(const float* __restrict__ h,
        const float* __restrict__ g, const float* __restrict__ be,
        unsigned short* __restrict__ xo, float* __restrict__ fo) {
    int row = blockIdx.x, tid = threadIdx.x;
    float4 v = *(const float4*)(h + (size_t)row * 1024 + tid * 4);
    float s = v.x + v.y + v.z + v.w;
    for (int off = 32; off; off >>= 1) s += __shfl_down(s, off);
    __shared__ float red[8];
    int wid = tid >> 6, lane = tid & 63;
    if (!lane) red[wid] = s;
    __syncthreads();
    float mean = (red[0] + red[1] + red[2] + red[3]) * (1.f / 1024.f);
    float dx = v.x - mean, dy = v.y - mean, dz = v.z - mean, dw = v.w - mean;
    float q = dx * dx + dy * dy + dz * dz + dw * dw;
    for (int off = 32; off; off >>= 1) q += __shfl_down(q, off);
    if (!lane) red[4 + wid] = q;
    __syncthreads();
    float var = (red[4] + red[5] + red[6] + red[7]) * (1.f / 1024.f);
    float inv = 1.0f / sqrtf(var + 1e-5f);
    float4 gv = *(const float4*)(g + tid * 4);
    float4 bv = *(const float4*)(be + tid * 4);
    float y0 = dx * inv * gv.x + bv.x;
    float y1 = dy * inv * gv.y + bv.y;
    float y2 = dz * inv * gv.z + bv.z;
    float y3 = dw * inv * gv.w + bv.w;
    if (BF16OUT) {
        ushort4 o;
        o.x = f2bf(y0); o.y = f2bf(y1); o.z = f2bf(y2); o.w = f2bf(y3);
        *(ushort4*)(xo + (size_t)row * 1024 + tid * 4) = o;
    } else {
        *(float4*)(fo + (size_t)row * 1024 + tid * 4) = make_float4(y0, y1, y2, y3);
    }
}

// ---------------- LoRA-A via MFMA: tmp[M][32] = bf16( A[M][K] @ laT[32][K]^T ) ----------------
// 1 wave / block, 16 rows / block, no LDS, no barriers (loads pipeline freely).
__global__ __launch_bounds__(64) void k_lora_mfma(const unsigned short* __restrict__ A,
        const unsigned short* __restrict__ laT, unsigned short* __restrict__ tmp, int K) {
    int rowBase = blockIdx.x * 16;
    int lane = threadIdx.x;
    int lrow = lane & 15, lk8 = (lane >> 4) * 8;
    f32x4 acc0 = {0.f, 0.f, 0.f, 0.f}, acc1 = {0.f, 0.f, 0.f, 0.f};
    const unsigned short* arow = A + (size_t)(rowBase + lrow) * K + lk8;
    const unsigned short* b0p = laT + (size_t)lrow * K + lk8;
    const unsigned short* b1p = laT + (size_t)(16 + lrow) * K + lk8;
#pragma unroll 2
    for (int kt = 0; kt < K; kt += 32) {
        bf16x8 af = *(const bf16x8*)(arow + kt);
        bf16x8 b0 = *(const bf16x8*)(b0p + kt);
        bf16x8 b1 = *(const bf16x8*)(b1p + kt);
        acc0 = __builtin_amdgcn_mfma_f32_16x16x32_bf16(af, b0, acc0, 0, 0, 0);
        acc1 = __builtin_amdgcn_mfma_f32_16x16x32_bf16(af, b1, acc1, 0, 0, 0);
    }
    int lq = lane >> 4;
#pragma unroll
    for (int rg = 0; rg < 4; ++rg) {
        int row = rowBase + lq * 4 + rg;
        tmp[(size_t)row * 32 + lrow] = f2bf(acc0[rg]);
        tmp[(size_t)row * 32 + 16 + lrow] = f2bf(acc1[rg]);
    }
}

// ---------------- per-layer weight prep: f32 [K][N] -> bf16 [N][K] ----------------
// lb tensors pre-scaled by 2 (LoRA SCALING); la tensors transposed to [32][K].
__global__ __launch_bounds__(256) void k_prep(
        const float* aw, const float* pw, const float* fw, const float* mw,
        const float* alb, const float* plb, const float* flb, const float* mlb,
        const float* ala, const float* pla, const float* fla, const float* mla,
        unsigned short* WTq, unsigned short* WTp, unsigned short* WTf, unsigned short* WTm,
        unsigned short* LTq, unsigned short* LTp, unsigned short* LTf, unsigned short* LTm,
        unsigned short* LAq, unsigned short* LAp, unsigned short* LAf, unsigned short* LAm) {
    int bid = blockIdx.x;
    const float* src; unsigned short* dst; int K, N, ntn, local; float scale = 1.f;
    if      (bid < 768)  { src = aw;  dst = WTq; K = 1024; N = 3072; ntn = 48; local = bid; }
    else if (bid < 1024) { src = pw;  dst = WTp; K = 1024; N = 1024; ntn = 16; local = bid - 768; }
    else if (bid < 2048) { src = fw;  dst = WTf; K = 1024; N = 4096; ntn = 64; local = bid - 1024; }
    else if (bid < 3072) { src = mw;  dst = WTm; K = 4096; N = 1024; ntn = 16; local = bid - 2048; }
    else if (bid < 3120) { src = alb; dst = LTq; K = 32;   N = 3072; ntn = 48; local = bid - 3072; scale = 2.f; }
    else if (bid < 3136) { src = plb; dst = LTp; K = 32;   N = 1024; ntn = 16; local = bid - 3120; scale = 2.f; }
    else if (bid < 3200) { src = flb; dst = LTf; K = 32;   N = 4096; ntn = 64; local = bid - 3136; scale = 2.f; }
    else if (bid < 3216) { src = mlb; dst = LTm; K = 32;   N = 1024; ntn = 16; local = bid - 3200; scale = 2.f; }
    else if (bid < 3232) { src = ala; dst = LAq; K = 1024; N = 32;   ntn = 1;  local = bid - 3216; }
    else if (bid < 3248) { src = pla; dst = LAp; K = 1024; N = 32;   ntn = 1;  local = bid - 3232; }
    else if (bid < 3264) { src = fla; dst = LAf; K = 1024; N = 32;   ntn = 1;  local = bid - 3248; }
    else                 { src = mla; dst = LAm; K = 4096; N = 32;   ntn = 1;  local = bid - 3264; }
    int kt = local / ntn, nt = local % ntn;
    int k0 = kt * 64, n0 = nt * 64;
    __shared__ unsigned short Tl[64][72];
    int tid = threadIdx.x;
    int cr = tid >> 6;     // 0..3
    int cc = tid & 63;     // 0..63
#pragma unroll
    for (int p = 0; p < 16; ++p) {
        int kl = p * 4 + cr;
        if (k0 + kl < K && n0 + cc < N) Tl[kl][cc] = f2bf(src[(size_t)(k0 + kl) * N + n0 + cc] * scale);
    }
    __syncthreads();
#pragma unroll
    for (int p = 0; p < 16; ++p) {
        int nl = p * 4 + cr;
        int kl = cc;
        if (k0 + kl < K && n0 + nl < N) dst[(size_t)(n0 + nl) * K + k0 + kl] = Tl[kl][nl];
    }
}

// ---------------- GEMM: out[M][N] = A_bf16[M][K] @ WT_bf16[N][K]^T + bias (+LoRA K-ext) ----------------
// m97 structure: linear [128][32] LDS tiles staged via global_load_lds width=16.
// EPI: 0 = write f32 ; 1 = +residual, write f32 ; 2 = GELU, write bf16
template <int EPI>
__global__ __launch_bounds__(256) void k_gemm(
        const unsigned short* __restrict__ A, const unsigned short* __restrict__ WT,
        const float* __restrict__ bias, const unsigned short* __restrict__ tmpA,
        const unsigned short* __restrict__ lbT, const float* __restrict__ res,
        float* __restrict__ outF, unsigned short* __restrict__ outH, int N, int K) {
    __shared__ unsigned short Al[128 * 32];
    __shared__ unsigned short Bl[128 * 32];
    int tid = threadIdx.x;
    int nBase = blockIdx.x * 128, rowBase = blockIdx.y * 128;
    int w = tid >> 6, lane = tid & 63;
    int wr = w >> 1, wc = w & 1;
    int lrow = lane & 15, lk8 = (lane >> 4) * 8;
    // staging geometry: wave w covers rows [w*32, w*32+32); issue p covers 16 rows.
    // lane l -> row (w*32 + p*16 + (l>>2)), k-elems (l&3)*8  (matches lane*16B linear LDS fill)
    int srow = w * 32 + (lane >> 2);
    int scol = (lane & 3) * 8;
    f32x4 acc[4][4];
#pragma unroll
    for (int i = 0; i < 4; ++i)
#pragma unroll
        for (int j = 0; j < 4; ++j) acc[i][j] = f32x4{0.f, 0.f, 0.f, 0.f};
    int nk = K >> 5;
    for (int kt = 0; kt <= nk; ++kt) {
        bool mn = kt < nk;
        const unsigned short* sa0;
        const unsigned short* sa1;
        const unsigned short* sb0;
        const unsigned short* sb1;
        if (mn) {
            sa0 = A + (size_t)(rowBase + srow) * K + kt * 32 + scol;
            sa1 = A + (size_t)(rowBase + srow + 16) * K + kt * 32 + scol;
            sb0 = WT + (size_t)(nBase + srow) * K + kt * 32 + scol;
            sb1 = WT + (size_t)(nBase + srow + 16) * K + kt * 32 + scol;
        } else {
            sa0 = tmpA + (size_t)(rowBase + srow) * 32 + scol;
            sa1 = tmpA + (size_t)(rowBase + srow + 16) * 32 + scol;
            sb0 = lbT + (size_t)(nBase + srow) * 32 + scol;
            sb1 = lbT + (size_t)(nBase + srow + 16) * 32 + scol;
        }
        __syncthreads();   // previous tile fully consumed
        GL2LDS(sa0, &Al[(w * 32) * 32]);
        GL2LDS(sa1, &Al[(w * 32 + 16) * 32]);
        GL2LDS(sb0, &Bl[(w * 32) * 32]);
        GL2LDS(sb1, &Bl[(w * 32 + 16) * 32]);
        __syncthreads();   // drains vmcnt(0): tile resident
        bf16x8 af[4], bfr[4];
#pragma unroll
        for (int mt = 0; mt < 4; ++mt) af[mt] = *(const bf16x8*)&Al[(wr * 64 + mt * 16 + lrow) * 32 + lk8];
#pragma unroll
        for (int nt = 0; nt < 4; ++nt) bfr[nt] = *(const bf16x8*)&Bl[(wc * 64 + nt * 16 + lrow) * 32 + lk8];
#pragma unroll
        for (int mt = 0; mt < 4; ++mt)
#pragma unroll
            for (int nt = 0; nt < 4; ++nt)
                acc[mt][nt] = __builtin_amdgcn_mfma_f32_16x16x32_bf16(af[mt], bfr[nt], acc[mt][nt], 0, 0, 0);
    }
    int lq = lane >> 4;
#pragma unroll
    for (int nt = 0; nt < 4; ++nt) {
        int col = nBase + wc * 64 + nt * 16 + lrow;
        float bv = bias[col];
#pragma unroll
        for (int mt = 0; mt < 4; ++mt) {
            int row0 = rowBase + wr * 64 + mt * 16 + lq * 4;
#pragma unroll
            for (int rg = 0; rg < 4; ++rg) {
                int row = row0 + rg;
                float v = acc[mt][nt][rg] + bv;
                size_t idx = (size_t)row * N + col;
                if (EPI == 1) v += res[idx];
                if (EPI == 2) {
                    v = 0.5f * v * (1.f + erff(v * 0.70710678118654752f));
                    outH[idx] = f2bf(v);
                } else {
                    outF[idx] = v;
                }
            }
        }
    }
}

// ---------------- split heads + KV fake-quant; V stored transposed per head ----------------
__global__ __launch_bounds__(256) void k_headq(const float* __restrict__ qkv,
        const float* __restrict__ kvmin, const float* __restrict__ kvmax, int layer,
        unsigned short* __restrict__ qh, unsigned short* __restrict__ kh,
        unsigned short* __restrict__ vh) {
    int t0 = blockIdx.x * 64;
    int bh = blockIdx.y;
    int b = bh >> 4, hh = bh & 15;
    float mnv = kvmin[layer], mxv = kvmax[layer];
    float s = (mxv - mnv) * (1.f / 255.f);
    float zp = rintf(-mnv / s);
    float inv_s = 1.f / s;
    int tid = threadIdx.x;
    int rl = tid >> 2, dseg = (tid & 3) * 16;
    __shared__ unsigned short Vl[64][72];
    size_t base = ((size_t)(b * 1024 + t0 + rl)) * 3072 + hh * 64 + dseg;
    unsigned short t16[16];
    // q
#pragma unroll
    for (int c = 0; c < 4; ++c) {
        float4 v = *(const float4*)(qkv + base + c * 4);
        t16[c * 4 + 0] = f2bf(v.x); t16[c * 4 + 1] = f2bf(v.y);
        t16[c * 4 + 2] = f2bf(v.z); t16[c * 4 + 3] = f2bf(v.w);
    }
    size_t obase = ((size_t)bh * 1024 + t0 + rl) * 64 + dseg;
    *(uint4*)(qh + obase) = *(uint4*)&t16[0];
    *(uint4*)(qh + obase + 8) = *(uint4*)&t16[8];
    // k (fake-quant)
#pragma unroll
    for (int c = 0; c < 4; ++c) {
        float4 v = *(const float4*)(qkv + base + 1024 + c * 4);
        float vals[4] = {v.x, v.y, v.z, v.w};
#pragma unroll
        for (int j = 0; j < 4; ++j) {
            float qv = rintf(vals[j] * inv_s) + zp;
            qv = fminf(fmaxf(qv, 0.f), 255.f);
            t16[c * 4 + j] = f2bf((qv - zp) * s);
        }
    }
    *(uint4*)(kh + obase) = *(uint4*)&t16[0];
    *(uint4*)(kh + obase + 8) = *(uint4*)&t16[8];
    // v (fake-quant) -> LDS -> transposed store
#pragma unroll
    for (int c = 0; c < 4; ++c) {
        float4 v = *(const float4*)(qkv + base + 2048 + c * 4);
        float vals[4] = {v.x, v.y, v.z, v.w};
#pragma unroll
        for (int j = 0; j < 4; ++j) {
            float qv = rintf(vals[j] * inv_s) + zp;
            qv = fminf(fmaxf(qv, 0.f), 255.f);
            Vl[rl][dseg + c * 4 + j] = f2bf((qv - zp) * s);
        }
    }
    __syncthreads();
    int dl = rl, tseg = dseg;
#pragma unroll
    for (int j = 0; j < 16; ++j) t16[j] = Vl[tseg + j][dl];
    size_t vbase = ((size_t)bh * 64 + dl) * 1024 + t0 + tseg;
    *(uint4*)(vh + vbase) = *(uint4*)&t16[0];
    *(uint4*)(vh + vbase + 8) = *(uint4*)&t16[8];
}

// ---------------- flash attention (causal), 64 q-rows/block, 4 waves ----------------
__global__ __launch_bounds__(256) void k_attn(const unsigned short* __restrict__ qh,
        const unsigned short* __restrict__ kh, const unsigned short* __restrict__ vh,
        unsigned short* __restrict__ o) {
    int qb = blockIdx.x, bh = blockIdx.y;
    int b = bh >> 4, hh = bh & 15;
    int tid = threadIdx.x, w = tid >> 6, lane = tid & 63;
    int lrow = lane & 15, lq = lane >> 4, lk8 = lq * 8;
    __shared__ unsigned short Kl[64][72];
    __shared__ unsigned short Vt[64][72];
    __shared__ unsigned short Pl[4][16][72];
    int qrow = qb * 64 + w * 16 + lrow;
    bf16x8 aq[2];
    aq[0] = *(const bf16x8*)(qh + ((size_t)bh * 1024 + qrow) * 64 + lk8);
    aq[1] = *(const bf16x8*)(qh + ((size_t)bh * 1024 + qrow) * 64 + 32 + lk8);
    f32x4 od[4];
#pragma unroll
    for (int i = 0; i < 4; ++i) od[i] = f32x4{0.f, 0.f, 0.f, 0.f};
    float mrun[4] = {-1e30f, -1e30f, -1e30f, -1e30f};
    float lrun[4] = {0.f, 0.f, 0.f, 0.f};
    int rl = tid >> 2, seg = (tid & 3) * 16;
    for (int kb = 0; kb <= qb; ++kb) {
        __syncthreads();
        {
            size_t kbase = ((size_t)bh * 1024 + kb * 64 + rl) * 64 + seg;
            *(uint4*)&Kl[rl][seg] = *(const uint4*)(kh + kbase);
            *(uint4*)&Kl[rl][seg + 8] = *(const uint4*)(kh + kbase + 8);
            size_t vbase = ((size_t)bh * 64 + rl) * 1024 + kb * 64 + seg;
            *(uint4*)&Vt[rl][seg] = *(const uint4*)(vh + vbase);
            *(uint4*)&Vt[rl][seg + 8] = *(const uint4*)(vh + vbase + 8);
        }
        __syncthreads();
        f32x4 st[4];
#pragma unroll
        for (int ktile = 0; ktile < 4; ++ktile) {
            f32x4 sacc = f32x4{0.f, 0.f, 0.f, 0.f};
#pragma unroll
            for (int dh = 0; dh < 2; ++dh) {
                bf16x8 bk = *(const bf16x8*)&Kl[ktile * 16 + lrow][dh * 32 + lk8];
                sacc = __builtin_amdgcn_mfma_f32_16x16x32_bf16(aq[dh], bk, sacc, 0, 0, 0);
            }
            st[ktile] = sacc * 0.125f;   // 1/sqrt(64)
        }
        if (kb == qb) {
#pragma unroll
            for (int ktile = 0; ktile < 4; ++ktile) {
                int kidx = kb * 64 + ktile * 16 + lrow;
#pragma unroll
                for (int rg = 0; rg < 4; ++rg) {
                    int qidx = qb * 64 + w * 16 + lq * 4 + rg;
                    if (kidx > qidx) st[ktile][rg] = -1e30f;
                }
            }
        }
        float corr[4];
#pragma unroll
        for (int rg = 0; rg < 4; ++rg) {
            float x = fmaxf(fmaxf(st[0][rg], st[1][rg]), fmaxf(st[2][rg], st[3][rg]));
            x = fmaxf(x, __shfl_xor(x, 1));
            x = fmaxf(x, __shfl_xor(x, 2));
            x = fmaxf(x, __shfl_xor(x, 4));
            x = fmaxf(x, __shfl_xor(x, 8));
            float mnew = fmaxf(mrun[rg], x);
            float sum = 0.f;
#pragma unroll
            for (int ktile = 0; ktile < 4; ++ktile) {
                st[ktile][rg] = expf(st[ktile][rg] - mnew);
                sum += st[ktile][rg];
            }
            sum += __shfl_xor(sum, 1);
            sum += __shfl_xor(sum, 2);
            sum += __shfl_xor(sum, 4);
            sum += __shfl_xor(sum, 8);
            corr[rg] = expf(mrun[rg] - mnew);
            lrun[rg] = lrun[rg] * corr[rg] + sum;
            mrun[rg] = mnew;
        }
#pragma unroll
        for (int dt = 0; dt < 4; ++dt)
#pragma unroll
            for (int rg = 0; rg < 4; ++rg) od[dt][rg] *= corr[rg];
#pragma unroll
        for (int ktile = 0; ktile < 4; ++ktile)
#pragma unroll
            for (int rg = 0; rg < 4; ++rg)
                Pl[w][lq * 4 + rg][ktile * 16 + lrow] = f2bf(st[ktile][rg]);
        __syncthreads();
        bf16x8 pa[2];
        pa[0] = *(const bf16x8*)&Pl[w][lrow][lk8];
        pa[1] = *(const bf16x8*)&Pl[w][lrow][32 + lk8];
#pragma unroll
        for (int dt = 0; dt < 4; ++dt) {
#pragma unroll
            for (int kh2 = 0; kh2 < 2; ++kh2) {
                bf16x8 bv = *(const bf16x8*)&Vt[dt * 16 + lrow][kh2 * 32 + lk8];
                od[dt] = __builtin_amdgcn_mfma_f32_16x16x32_bf16(pa[kh2], bv, od[dt], 0, 0, 0);
            }
        }
    }
#pragma unroll
    for (int dt = 0; dt < 4; ++dt) {
#pragma unroll
        for (int rg = 0; rg < 4; ++rg) {
            int row = qb * 64 + w * 16 + lq * 4 + rg;
            float val = od[dt][rg] / lrun[rg];
            o[((size_t)(b * 1024 + row)) * 1024 + hh * 64 + dt * 16 + lrow] = f2bf(val);
        }
    }
}

// ---------------- host orchestration ----------------
extern "C" void kernel_launch(void* const* d_in, const int* in_sizes, int n_in,
                              void* d_out, int out_size, void* d_ws, size_t ws_size,
                              hipStream_t stream) {
    const int*   ids      = (const int*)d_in[0];
    const float* wte      = (const float*)d_in[1];
    const float* wpe      = (const float*)d_in[2];
    const float* ln1_g    = (const float*)d_in[3];
    const float* ln1_b    = (const float*)d_in[4];
    const float* attn_w   = (const float*)d_in[5];
    const float* attn_b   = (const float*)d_in[6];
    const float* attn_la  = (const float*)d_in[7];
    const float* attn_lb  = (const float*)d_in[8];
    const float* proj_w   = (const float*)d_in[9];
    const float* proj_b   = (const float*)d_in[10];
    const float* proj_la  = (const float*)d_in[11];
    const float* proj_lb  = (const float*)d_in[12];
    const float* ln2_g    = (const float*)d_in[13];
    const float* ln2_b    = (const float*)d_in[14];
    const float* fc_w     = (const float*)d_in[15];
    const float* fc_b     = (const float*)d_in[16];
    const float* fc_la    = (const float*)d_in[17];
    const float* fc_lb    = (const float*)d_in[18];
    const float* mproj_w  = (const float*)d_in[19];
    const float* mproj_b  = (const float*)d_in[20];
    const float* mproj_la = (const float*)d_in[21];
    const float* mproj_lb = (const float*)d_in[22];
    const float* kv_min   = (const float*)d_in[23];
    const float* kv_max   = (const float*)d_in[24];
    const float* lnf_g    = (const float*)d_in[25];
    const float* lnf_b    = (const float*)d_in[26];

    char* ws = (char*)d_ws;
    size_t off = 0;
    auto alloc = [&](size_t bytes) -> char* {
        char* p = ws + off;
        off = (off + bytes + 255) & ~(size_t)255;
        return p;
    };
    float*          h   = (float*)alloc(4096ull * 1024 * 4);
    unsigned short* xb  = (unsigned short*)alloc(4096ull * 1024 * 2);
    float*          qkv = (float*)alloc(4096ull * 3072 * 4);
    unsigned short* tmp = (unsigned short*)alloc(4096ull * 32 * 2);
    unsigned short* qhb = (unsigned short*)alloc(64ull * 1024 * 64 * 2);
    unsigned short* khb = (unsigned short*)alloc(64ull * 1024 * 64 * 2);
    unsigned short* vhb = (unsigned short*)alloc(64ull * 64 * 1024 * 2);
    unsigned short* ob  = (unsigned short*)alloc(4096ull * 1024 * 2);
    unsigned short* mb  = (unsigned short*)alloc(4096ull * 4096 * 2);
    unsigned short* WTq = (unsigned short*)alloc(3072ull * 1024 * 2);
    unsigned short* WTp = (unsigned short*)alloc(1024ull * 1024 * 2);
    unsigned short* WTf = (unsigned short*)alloc(4096ull * 1024 * 2);
    unsigned short* WTm = (unsigned short*)alloc(1024ull * 4096 * 2);
    unsigned short* LTq = (unsigned short*)alloc(3072ull * 32 * 2);
    unsigned short* LTp = (unsigned short*)alloc(1024ull * 32 * 2);
    unsigned short* LTf = (unsigned short*)alloc(4096ull * 32 * 2);
    unsigned short* LTm = (unsigned short*)alloc(1024ull * 32 * 2);
    unsigned short* LAq = (unsigned short*)alloc(32ull * 1024 * 2);
    unsigned short* LAp = (unsigned short*)alloc(32ull * 1024 * 2);
    unsigned short* LAf = (unsigned short*)alloc(32ull * 1024 * 2);
    unsigned short* LAm = (unsigned short*)alloc(32ull * 4096 * 2);

    k_embed<<<4096, 256, 0, stream>>>(ids, wte, wpe, h);
    for (int l = 0; l < 12; ++l) {
        k_prep<<<3328, 256, 0, stream>>>(
            attn_w + (size_t)l * 1024 * 3072, proj_w + (size_t)l * 1024 * 1024,
            fc_w + (size_t)l * 1024 * 4096, mproj_w + (size_t)l * 4096 * 1024,
            attn_lb + (size_t)l * 32 * 3072, proj_lb + (size_t)l * 32 * 1024,
            fc_lb + (size_t)l * 32 * 4096, mproj_lb + (size_t)l * 32 * 1024,
            attn_la + (size_t)l * 1024 * 32, proj_la + (size_t)l * 1024 * 32,
            fc_la + (size_t)l * 1024 * 32, mproj_la + (size_t)l * 4096 * 32,
            WTq, WTp, WTf, WTm, LTq, LTp, LTf, LTm, LAq, LAp, LAf, LAm);
        k_ln<true><<<4096, 256, 0, stream>>>(h, ln1_g + l * 1024, ln1_b + l * 1024, xb, nullptr);
        k_lora_mfma<<<256, 64, 0, stream>>>(xb, LAq, tmp, 1024);
        k_gemm<0><<<dim3(24, 32), 256, 0, stream>>>(xb, WTq, attn_b + l * 3072, tmp, LTq,
                                                    nullptr, qkv, nullptr, 3072, 1024);
        k_headq<<<dim3(16, 64), 256, 0, stream>>>(qkv, kv_min, kv_max, l, qhb, khb, vhb);
        k_attn<<<dim3(16, 64), 256, 0, stream>>>(qhb, khb, vhb, ob);
        k_lora_mfma<<<256, 64, 0, stream>>>(ob, LAp, tmp, 1024);
        k_gemm<1><<<dim3(8, 32), 256, 0, stream>>>(ob, WTp, proj_b + l * 1024, tmp, LTp,
                                                   h, h, nullptr, 1024, 1024);
        k_ln<true><<<4096, 256, 0, stream>>>(h, ln2_g + l * 1024, ln2_b + l * 1024, xb, nullptr);
        k_lora_mfma<<<256, 64, 0, stream>>>(xb, LAf, tmp, 1024);
        k_gemm<2><<<dim3(32, 32), 256, 0, stream>>>(xb, WTf, fc_b + l * 4096, tmp, LTf,
                                                    nullptr, nullptr, mb, 4096, 1024);
        k_lora_mfma<<<256, 64, 0, stream>>>(mb, LAm, tmp, 4096);
        k_gemm<1><<<dim3(8, 32), 256, 0, stream>>>(mb, WTm, mproj_b + l * 1024, tmp, LTm,
                                                   h, h, nullptr, 1024, 4096);
    }
    k_ln<false><<<4096, 256, 0, stream>>>(h, lnf_g, lnf_b, nullptr, (float*)d_out);
}